// Round 22
// baseline (136.092 us; speedup 1.0000x reference)
//
#include <hip/hip_runtime.h>
#include <math.h>

#define G 64
#define NDIM 512
#define FIN 7
#define HID 64
#define CLS 2
#define KPOOL 128

typedef unsigned long long u64;

__device__ __forceinline__ float wred64(float v){
  #pragma unroll
  for (int o = 32; o > 0; o >>= 1) v += __shfl_xor(v, o, 64);
  return v;
}

// ---- build transposed bitmasks: maskT[g][u][i] bit l = adj[g][i][u*64+l] ---
__global__ __launch_bounds__(256) void mask_kernel(const float* __restrict__ adj,
                                                   u64* __restrict__ maskT){
  const int wid = threadIdx.x >> 6, lane = threadIdx.x & 63;
  const int row = blockIdx.x * 4 + wid;          // [0, G*NDIM)
  const int g = row >> 9, i = row & 511;
  const float* ar = adj + (size_t)row * NDIM;
  u64 b[8];
  #pragma unroll
  for (int u = 0; u < 8; u++)
    b[u] = __ballot(ar[u * 64 + lane] != 0.0f);
  if (lane == 0){
    u64* mt = maskT + (size_t)g * 8 * NDIM + i;
    #pragma unroll
    for (int u = 0; u < 8; u++) mt[(size_t)u * NDIM] = b[u];
  }
}

// ---- mega v5: B=4 blocks/graph, 512 threads, 1 row/thread, stride-12 z.
//      Walks use 4 INDEPENDENT chains (words 4h..4h+3): 4 serial-free ctz
//      chains, 8 outstanding ds_read_b128 -> hides ~120cy LDS latency
//      (r8 m_kernel recipe: VALUBusy 12%->73%).
__global__ __launch_bounds__(512) void mega_kernel(
    const u64* __restrict__ maskT, const float* __restrict__ x,
    const float* __restrict__ panw, const float* __restrict__ w1,
    const float* __restrict__ b1, const float* __restrict__ pvec,
    const float* __restrict__ beta,
    float* __restrict__ dvec, float* __restrict__ score,
    float* __restrict__ hbuf)
{
  __shared__ float deg_s[NDIM];                    // 2 KB
  __shared__ float d2_s[NDIM];                     // 2 KB
  __shared__ __align__(16) float zA[NDIM * 12];    // 24 KB
  __shared__ __align__(16) float zB[NDIM * 12];    // 24 KB
  __shared__ float Wl[576];                        // 2.3 KB

  const int bid = blockIdx.x;                      // [0,256)
  const int g = (bid & 7) + 8 * ((bid >> 3) & 7);  // graph -> XCD bid%8
  const int chunk = bid >> 6;                      // [0,4): own rows [128c,+128)
  const int t = threadIdx.x;                       // row [0,512)

  u64 mk[8];
  #pragma unroll
  for (int u = 0; u < 8; u++)
    mk[u] = maskT[(size_t)g * 8 * NDIM + (size_t)u * NDIM + t];
  float xr[FIN];
  {
    const float* px = x + ((size_t)g * NDIM + t) * FIN;
    #pragma unroll
    for (int f = 0; f < FIN; f++) xr[f] = px[f];
  }
  const float w0 = panw[0], ww1 = panw[1], ww2 = panw[2], ww3 = panw[3];
  const float c0 = w0, c1 = c0 * ww1, c2 = c1 * ww2, c3 = c2 * ww3;
  const bool own = (t >> 7) == chunk;

  float dg = 0.f;
  #pragma unroll
  for (int u = 0; u < 8; u++) dg += (float)__popcll(mk[u]);
  deg_s[t] = dg;
  __syncthreads();

  // ---- scalar 4-chain walk (exact ints; any order bit-identical) ----
#define SWALK4(SRC, OUT) { \
    float s0_ = 0.f, s1_ = 0.f, s2_ = 0.f, s3_ = 0.f; \
    _Pragma("unroll") \
    for (int h_ = 0; h_ < 2; h_++){ \
      u64 mA_ = mk[4*h_], mB_ = mk[4*h_+1], mC_ = mk[4*h_+2], mD_ = mk[4*h_+3]; \
      const float* sb_ = (SRC) + h_ * 256; \
      while (mA_ && mB_ && mC_ && mD_){ \
        int lA_ = __builtin_ctzll(mA_); mA_ &= mA_ - 1; \
        int lB_ = __builtin_ctzll(mB_); mB_ &= mB_ - 1; \
        int lC_ = __builtin_ctzll(mC_); mC_ &= mC_ - 1; \
        int lD_ = __builtin_ctzll(mD_); mD_ &= mD_ - 1; \
        s0_ += sb_[lA_]; s1_ += sb_[64 + lB_]; \
        s2_ += sb_[128 + lC_]; s3_ += sb_[192 + lD_]; \
      } \
      while (mA_){ int l_ = __builtin_ctzll(mA_); mA_ &= mA_ - 1; s0_ += sb_[l_]; } \
      while (mB_){ int l_ = __builtin_ctzll(mB_); mB_ &= mB_ - 1; s1_ += sb_[64 + l_]; } \
      while (mC_){ int l_ = __builtin_ctzll(mC_); mC_ &= mC_ - 1; s2_ += sb_[128 + l_]; } \
      while (mD_){ int l_ = __builtin_ctzll(mD_); mD_ &= mD_ - 1; s3_ += sb_[192 + l_]; } \
    } \
    (OUT) = (s0_ + s1_) + (s2_ + s3_); \
  }

  // ---- vector(8) 4-chain walk over stride-12 table ----
#define VWALK4(SRC, ACC) { \
    float a0_[8] = {0,0,0,0,0,0,0,0}, a1_[8] = {0,0,0,0,0,0,0,0}; \
    float a2_[8] = {0,0,0,0,0,0,0,0}, a3_[8] = {0,0,0,0,0,0,0,0}; \
    _Pragma("unroll") \
    for (int h_ = 0; h_ < 2; h_++){ \
      u64 mA_ = mk[4*h_], mB_ = mk[4*h_+1], mC_ = mk[4*h_+2], mD_ = mk[4*h_+3]; \
      const int base_ = h_ * 256; \
      while (mA_ && mB_ && mC_ && mD_){ \
        int lA_ = __builtin_ctzll(mA_); mA_ &= mA_ - 1; \
        int lB_ = __builtin_ctzll(mB_); mB_ &= mB_ - 1; \
        int lC_ = __builtin_ctzll(mC_); mC_ &= mC_ - 1; \
        int lD_ = __builtin_ctzll(mD_); mD_ &= mD_ - 1; \
        const float4* pA_ = (const float4*)((SRC) + (base_ + lA_) * 12); \
        const float4* pB_ = (const float4*)((SRC) + (base_ + 64 + lB_) * 12); \
        const float4* pC_ = (const float4*)((SRC) + (base_ + 128 + lC_) * 12); \
        const float4* pD_ = (const float4*)((SRC) + (base_ + 192 + lD_) * 12); \
        float4 vA0_ = pA_[0], vA1_ = pA_[1]; \
        float4 vB0_ = pB_[0], vB1_ = pB_[1]; \
        float4 vC0_ = pC_[0], vC1_ = pC_[1]; \
        float4 vD0_ = pD_[0], vD1_ = pD_[1]; \
        a0_[0] += vA0_.x; a0_[1] += vA0_.y; a0_[2] += vA0_.z; a0_[3] += vA0_.w; \
        a0_[4] += vA1_.x; a0_[5] += vA1_.y; a0_[6] += vA1_.z; a0_[7] += vA1_.w; \
        a1_[0] += vB0_.x; a1_[1] += vB0_.y; a1_[2] += vB0_.z; a1_[3] += vB0_.w; \
        a1_[4] += vB1_.x; a1_[5] += vB1_.y; a1_[6] += vB1_.z; a1_[7] += vB1_.w; \
        a2_[0] += vC0_.x; a2_[1] += vC0_.y; a2_[2] += vC0_.z; a2_[3] += vC0_.w; \
        a2_[4] += vC1_.x; a2_[5] += vC1_.y; a2_[6] += vC1_.z; a2_[7] += vC1_.w; \
        a3_[0] += vD0_.x; a3_[1] += vD0_.y; a3_[2] += vD0_.z; a3_[3] += vD0_.w; \
        a3_[4] += vD1_.x; a3_[5] += vD1_.y; a3_[6] += vD1_.z; a3_[7] += vD1_.w; \
      } \
      while (mA_){ int l_ = __builtin_ctzll(mA_); mA_ &= mA_ - 1; \
        const float4* p_ = (const float4*)((SRC) + (base_ + l_) * 12); \
        float4 v0_ = p_[0], v1_ = p_[1]; \
        a0_[0] += v0_.x; a0_[1] += v0_.y; a0_[2] += v0_.z; a0_[3] += v0_.w; \
        a0_[4] += v1_.x; a0_[5] += v1_.y; a0_[6] += v1_.z; a0_[7] += v1_.w; } \
      while (mB_){ int l_ = __builtin_ctzll(mB_); mB_ &= mB_ - 1; \
        const float4* p_ = (const float4*)((SRC) + (base_ + 64 + l_) * 12); \
        float4 v0_ = p_[0], v1_ = p_[1]; \
        a1_[0] += v0_.x; a1_[1] += v0_.y; a1_[2] += v0_.z; a1_[3] += v0_.w; \
        a1_[4] += v1_.x; a1_[5] += v1_.y; a1_[6] += v1_.z; a1_[7] += v1_.w; } \
      while (mC_){ int l_ = __builtin_ctzll(mC_); mC_ &= mC_ - 1; \
        const float4* p_ = (const float4*)((SRC) + (base_ + 128 + l_) * 12); \
        float4 v0_ = p_[0], v1_ = p_[1]; \
        a2_[0] += v0_.x; a2_[1] += v0_.y; a2_[2] += v0_.z; a2_[3] += v0_.w; \
        a2_[4] += v1_.x; a2_[5] += v1_.y; a2_[6] += v1_.z; a2_[7] += v1_.w; } \
      while (mD_){ int l_ = __builtin_ctzll(mD_); mD_ &= mD_ - 1; \
        const float4* p_ = (const float4*)((SRC) + (base_ + 192 + l_) * 12); \
        float4 v0_ = p_[0], v1_ = p_[1]; \
        a3_[0] += v0_.x; a3_[1] += v0_.y; a3_[2] += v0_.z; a3_[3] += v0_.w; \
        a3_[4] += v1_.x; a3_[5] += v1_.y; a3_[6] += v1_.z; a3_[7] += v1_.w; } \
    } \
    _Pragma("unroll") \
    for (int e_ = 0; e_ < 8; e_++) (ACC)[e_] = (a0_[e_] + a1_[e_]) + (a2_[e_] + a3_[e_]); \
  }

  float d2;
  SWALK4(deg_s, d2)
  d2_s[t] = d2;
  __syncthreads();
  float d3;
  SWALK4(d2_s, d3)
  const float dd = rsqrtf(fmaxf(c0 + c1 * dg + c2 * d2 + c3 * d3, 1.0f));
  if (own) dvec[g * NDIM + t] = dd;
  *(float4*)(zA + t * 12)     = make_float4(dd, dd * xr[0], dd * xr[1], dd * xr[2]);
  *(float4*)(zA + t * 12 + 4) = make_float4(dd * xr[3], dd * xr[4], dd * xr[5], dd * xr[6]);
  __syncthreads();
  float aw1[8], aw2[8], aw3[8];
  VWALK4(zA, aw1)
  *(float4*)(zB + t * 12)     = make_float4(aw1[0], aw1[1], aw1[2], aw1[3]);
  *(float4*)(zB + t * 12 + 4) = make_float4(aw1[4], aw1[5], aw1[6], aw1[7]);
  __syncthreads();
  VWALK4(zB, aw2)
  *(float4*)(zA + t * 12)     = make_float4(aw2[0], aw2[1], aw2[2], aw2[3]);
  *(float4*)(zA + t * 12 + 4) = make_float4(aw2[4], aw2[5], aw2[6], aw2[7]);
  if (t < FIN * HID) Wl[t] = w1[t];
  if (t < HID){ Wl[448 + t] = pvec[t]; Wl[512 + t] = b1[t]; }
  __syncthreads();
  if (own){
    VWALK4(zA, aw3)
    const int row = g * NDIM + t;
    const float s2v = dd * (c0 * dd + c1 * aw1[0] + c2 * aw2[0] + c3 * aw3[0]);
    float yin[FIN];
    #pragma unroll
    for (int f = 0; f < FIN; f++){
      float zv = dd * xr[f];
      float y = c0 * zv;
      y += c1 * aw1[f + 1];
      y += c2 * aw2[f + 1];
      y += c3 * aw3[f + 1];
      yin[f] = dd * y;
    }
    float hv[HID];
    float s1 = 0.f;
    #pragma unroll
    for (int o = 0; o < HID; o++){
      float zz = Wl[512 + o];
      #pragma unroll
      for (int f = 0; f < FIN; f++) zz = fmaf(yin[f], Wl[f * HID + o], zz);
      hv[o] = fmaxf(zz, 0.f);
      s1 = fmaf(hv[o], Wl[448 + o], s1);
    }
    score[row] = tanhf(beta[0] * s1 + beta[1] * s2v);
    float* hr = hbuf + (size_t)row * HID;
    #pragma unroll
    for (int o = 0; o < HID; o++) hr[o] = hv[o];
  }
}

// ---- top-k rank selection + xp gather -------------------------------------
__global__ __launch_bounds__(512) void topk_kernel(const float* __restrict__ score,
                                                   const float* __restrict__ hbuf,
                                                   int* __restrict__ idxOut,
                                                   float* __restrict__ xp)
{
  const int g = blockIdx.x, t = threadIdx.x;        // 512
  __shared__ float sv[NDIM];
  sv[t] = score[g * NDIM + t];
  __syncthreads();
  const float v = sv[t];
  int rank = 0;
  #pragma unroll 8
  for (int j = 0; j < NDIM; j++){
    float u_ = sv[j];
    rank += (u_ > v || (u_ == v && j < t)) ? 1 : 0;
  }
  if (rank < KPOOL){
    idxOut[g * KPOOL + rank] = t;
    const float* hr = hbuf + ((size_t)g * NDIM + t) * HID;
    float* xr = xp + ((size_t)g * KPOOL + rank) * HID;
    #pragma unroll
    for (int o = 0; o < HID; o++) xr[o] = hr[o] * v;
  }
}

// ---- pool v3: merged-row A2p + transposed pair-packed arowT (r20 proven) --
__global__ __launch_bounds__(512) void pool_kernel(
    const u64* __restrict__ maskT, const int* __restrict__ idx,
    const float* __restrict__ dvec, const float* __restrict__ panw,
    float* __restrict__ Apool, float* __restrict__ di)
{
  const int b = blockIdx.x;
  const int g = b >> 3, rowgrp = b & 7;
  const int tid = threadIdx.x, w = tid >> 6, lane = tid & 63;
  __shared__ u64 mt[8][NDIM];                    // 32 KB
  __shared__ ushort arowT[NDIM][9];              // 9 KB (use col [w])
  __shared__ int idxs[KPOOL];
  __shared__ float dp[KPOOL];
  {
    const uint4* s4 = (const uint4*)(maskT + (size_t)g * 8 * NDIM);
    uint4* d4 = (uint4*)&mt[0][0];
    #pragma unroll
    for (int s = 0; s < 4; s++) d4[tid + 512 * s] = s4[tid + 512 * s];
  }
  if (tid < KPOOL){
    int ia = idx[g * KPOOL + tid];
    idxs[tid] = ia;
    dp[tid] = dvec[g * NDIM + ia];
  }
  __syncthreads();
  const int ir0 = idxs[rowgrp * 16 + w * 2];
  const int ir1 = idxs[rowgrp * 16 + w * 2 + 1];
  u64 rm0[8], rm1[8];
  #pragma unroll
  for (int u = 0; u < 8; u++){ rm0[u] = mt[u][ir0]; rm1[u] = mt[u][ir1]; }
  #pragma unroll
  for (int q = 0; q < 8; q++){
    const int k = q * 64 + lane;
    int p0 = 0, p1 = 0;
    #pragma unroll
    for (int u = 0; u < 8; u++){
      u64 cm = mt[u][k];
      p0 += (int)__popcll(cm & rm0[u]);
      p1 += (int)__popcll(cm & rm1[u]);
    }
    arowT[k][w] = (ushort)(p0 | (p1 << 8));
  }
  const int c0i = lane * 2, c1i = lane * 2 + 1;
  const int ic0 = idxs[c0i], ic1 = idxs[c1i];
  u64 cm0[8], cm1[8];
  #pragma unroll
  for (int u = 0; u < 8; u++){ cm0[u] = mt[u][ic0]; cm1[u] = mt[u][ic1]; }
  __syncthreads();
  int a300 = 0, a310 = 0, a301 = 0, a311 = 0;
  #pragma unroll
  for (int u = 0; u < 8; u++){
    u64 m0 = cm0[u];
    while (m0){
      int l = __builtin_ctzll(m0); m0 &= m0 - 1;
      ushort v = arowT[u * 64 + l][w];
      a300 += v & 0xFF; a310 += v >> 8;
    }
    u64 m1 = cm1[u];
    while (m1){
      int l = __builtin_ctzll(m1); m1 &= m1 - 1;
      ushort v = arowT[u * 64 + l][w];
      a301 += v & 0xFF; a311 += v >> 8;
    }
  }
  const ushort o0 = arowT[ic0][w];
  const ushort o1 = arowT[ic1][w];
  const float w0 = panw[0], ww1 = panw[1], ww2 = panw[2], ww3 = panw[3];
  const float cc0 = w0, cc1 = cc0 * ww1, cc2 = cc1 * ww2, cc3 = cc2 * ww3;
  const float dc0 = dp[c0i], dc1 = dp[c1i];
  float* Apg = Apool + (size_t)g * KPOOL * KPOOL;
  #pragma unroll
  for (int e = 0; e < 2; e++){
    const int r = rowgrp * 16 + w * 2 + e;
    const int ir = e ? ir1 : ir0;
    const float dpr = dp[r];
    const float a3c0 = (float)(e ? a310 : a300);
    const float a3c1 = (float)(e ? a311 : a301);
    const float a2c0 = (float)(e ? (o0 >> 8) : (o0 & 0xFF));
    const float a2c1 = (float)(e ? (o1 >> 8) : (o1 & 0xFF));
    float ab0 = (float)((cm0[ir >> 6] >> (ir & 63)) & 1ull);
    float ab1 = (float)((cm1[ir >> 6] >> (ir & 63)) & 1ull);
    float m0 = fmaf(cc3, a3c0, fmaf(cc2, a2c0, cc1 * ab0));
    float m1 = fmaf(cc3, a3c1, fmaf(cc2, a2c1, cc1 * ab1));
    if (r == c0i) m0 += cc0;
    if (r == c1i) m1 += cc0;
    float v0 = m0 * dpr * dc0;
    float v1 = m1 * dpr * dc1;
    if (r == c0i) v0 += 1.0f;
    if (r == c1i) v1 += 1.0f;
    *(float2*)&Apg[(size_t)r * KPOOL + c0i] = make_float2(v0, v1);
    float s = wred64(v0 + v1);
    if (lane == 0) di[g * KPOOL + r] = s > 0.f ? rsqrtf(s) : 0.f;
  }
}

// ---------------- pooled GCN: h2 = relu((An xp) W + b) ---------------------
__global__ __launch_bounds__(256) void gcn_kernel(
    const float* __restrict__ Apool, const float* __restrict__ di,
    const float* __restrict__ xp, const float* __restrict__ gw,
    const float* __restrict__ gb, float* __restrict__ h2)
{
  const int wid = threadIdx.x >> 6, lane = threadIdx.x & 63;
  const int row = blockIdx.x * 4 + wid;
  const int g = row >> 7, r = row & 127;
  const float dir = di[g * KPOOL + r];
  float acc = 0.f;
  for (int b = 0; b < KPOOL; b++){
    float an = Apool[(size_t)row * KPOOL + b] * dir * di[g * KPOOL + b];
    acc = fmaf(an, xp[((size_t)g * KPOOL + b) * HID + lane], acc);
  }
  __shared__ float ts[4][HID];
  ts[wid][lane] = acc;
  __syncthreads();
  float z = gb[lane];
  for (int f = 0; f < HID; f++) z = fmaf(ts[wid][f], gw[f * HID + lane], z);
  h2[(size_t)row * HID + lane] = fmaxf(z, 0.f);
}

// ---------------- head: pooled sum + linear + log_softmax ------------------
__global__ void head_kernel(const float* __restrict__ h2,
                            const float* __restrict__ lw,
                            const float* __restrict__ lb,
                            float* __restrict__ out)
{
  const int g = blockIdx.x;
  const int lane = threadIdx.x;
  float p = 0.f;
  for (int k = 0; k < KPOOL; k++) p += h2[((size_t)g * KPOOL + k) * HID + lane];
  float z0 = p * lw[lane * CLS + 0];
  float z1 = p * lw[lane * CLS + 1];
  z0 = wred64(z0);
  z1 = wred64(z1);
  if (lane == 0){
    float l0 = z0 + lb[0], l1 = z1 + lb[1];
    float m = fmaxf(l0, l1);
    float lse = m + logf(expf(l0 - m) + expf(l1 - m));
    out[g * CLS + 0] = l0 - lse;
    out[g * CLS + 1] = l1 - lse;
  }
}

extern "C" void kernel_launch(void* const* d_in, const int* in_sizes, int n_in,
                              void* d_out, int out_size, void* d_ws, size_t ws_size,
                              hipStream_t stream)
{
  const float* x    = (const float*)d_in[0];
  const float* adj  = (const float*)d_in[1];
  const float* panw = (const float*)d_in[2];
  const float* w1   = (const float*)d_in[3];
  const float* b1   = (const float*)d_in[4];
  const float* pvec = (const float*)d_in[5];
  const float* beta = (const float*)d_in[6];
  const float* gw   = (const float*)d_in[7];
  const float* gbv  = (const float*)d_in[8];
  const float* lw   = (const float*)d_in[9];
  const float* lb   = (const float*)d_in[10];
  float* out = (float*)d_out;

  char* ws = (char*)d_ws;
  const size_t NR = (size_t)G * NDIM;            // 32768 rows
  u64* maskT = (u64*)ws;                         // 2 MB
  char* p = ws + (1 << 21);
  float* dvec  = (float*)p;  p += NR * 4;
  float* score = (float*)p;  p += NR * 4;
  float* hbuf  = (float*)p;  p += NR * HID * 4;  // 8 MB
  int*   idx   = (int*)p;    p += (size_t)G * KPOOL * 4;
  float* xp    = (float*)p;  p += (size_t)G * KPOOL * HID * 4;
  float* Apool = (float*)p;  p += (size_t)G * KPOOL * KPOOL * 4;
  float* di    = (float*)p;  p += (size_t)G * KPOOL * 4;
  float* h2    = (float*)p;

  mask_kernel<<<G * NDIM / 4, 256, 0, stream>>>(adj, maskT);
  mega_kernel<<<256, 512, 0, stream>>>(maskT, x, panw, w1, b1, pvec, beta,
                                       dvec, score, hbuf);
  topk_kernel<<<G, 512, 0, stream>>>(score, hbuf, idx, xp);
  pool_kernel<<<G * 8, 512, 0, stream>>>(maskT, idx, dvec, panw, Apool, di);
  gcn_kernel<<<G * KPOOL / 4, 256, 0, stream>>>(Apool, di, xp, gw, gbv, h2);
  head_kernel<<<G, 64, 0, stream>>>(h2, lw, lb, out);
}

// Round 23
// 128.252 us; speedup vs baseline: 1.0611x; 1.0611x over previous
//
#include <hip/hip_runtime.h>
#include <math.h>

#define G 64
#define NDIM 512
#define FIN 7
#define HID 64
#define CLS 2
#define KPOOL 128

typedef unsigned long long u64;

__device__ __forceinline__ float wred64(float v){
  #pragma unroll
  for (int o = 32; o > 0; o >>= 1) v += __shfl_xor(v, o, 64);
  return v;
}

// ---- build transposed bitmasks: maskT[g][u][i] bit l = adj[g][i][u*64+l] ---
__global__ __launch_bounds__(256) void mask_kernel(const float* __restrict__ adj,
                                                   u64* __restrict__ maskT){
  const int wid = threadIdx.x >> 6, lane = threadIdx.x & 63;
  const int row = blockIdx.x * 4 + wid;          // [0, G*NDIM)
  const int g = row >> 9, i = row & 511;
  const float* ar = adj + (size_t)row * NDIM;
  u64 b[8];
  #pragma unroll
  for (int u = 0; u < 8; u++)
    b[u] = __ballot(ar[u * 64 + lane] != 0.0f);
  if (lane == 0){
    u64* mt = maskT + (size_t)g * 8 * NDIM + i;
    #pragma unroll
    for (int u = 0; u < 8; u++) mt[(size_t)u * NDIM] = b[u];
  }
}

// ---- mega v4 (r21 best): B=4 blocks/graph, 512 threads, 1 row/thread.
//      z/w tables: STRIDE-12 (48B) rows — 16B-aligned every row => each
//      neighbor read is 2x ds_read_b128. Row-start banks (12k)%32 cycle
//      8 positions — ~2-way. LDS 54.3 KB.
__global__ __launch_bounds__(512) void mega_kernel(
    const u64* __restrict__ maskT, const float* __restrict__ x,
    const float* __restrict__ panw, const float* __restrict__ w1,
    const float* __restrict__ b1, const float* __restrict__ pvec,
    const float* __restrict__ beta,
    float* __restrict__ dvec, float* __restrict__ score,
    float* __restrict__ hbuf)
{
  __shared__ float deg_s[NDIM];                    // 2 KB
  __shared__ float d2_s[NDIM];                     // 2 KB
  __shared__ __align__(16) float zA[NDIM * 12];    // 24 KB
  __shared__ __align__(16) float zB[NDIM * 12];    // 24 KB
  __shared__ float Wl[576];                        // 2.3 KB

  const int bid = blockIdx.x;                      // [0,256)
  const int g = (bid & 7) + 8 * ((bid >> 3) & 7);  // graph -> XCD bid%8
  const int chunk = bid >> 6;                      // [0,4): own rows [128c,+128)
  const int t = threadIdx.x;                       // row [0,512)

  u64 mk[8];
  #pragma unroll
  for (int u = 0; u < 8; u++)
    mk[u] = maskT[(size_t)g * 8 * NDIM + (size_t)u * NDIM + t];
  float xr[FIN];
  {
    const float* px = x + ((size_t)g * NDIM + t) * FIN;
    #pragma unroll
    for (int f = 0; f < FIN; f++) xr[f] = px[f];
  }
  const float w0 = panw[0], ww1 = panw[1], ww2 = panw[2], ww3 = panw[3];
  const float c0 = w0, c1 = c0 * ww1, c2 = c1 * ww2, c3 = c2 * ww3;
  const bool own = (t >> 7) == chunk;

  float dg = 0.f;
  #pragma unroll
  for (int u = 0; u < 8; u++) dg += (float)__popcll(mk[u]);
  deg_s[t] = dg;
  __syncthreads();
  float d2 = 0.f;
  #pragma unroll
  for (int u = 0; u < 8; u++){
    u64 mm = mk[u];
    while (mm){ int l = __builtin_ctzll(mm); mm &= mm - 1; d2 += deg_s[u * 64 + l]; }
  }
  d2_s[t] = d2;
  __syncthreads();
  float d3 = 0.f;
  #pragma unroll
  for (int u = 0; u < 8; u++){
    u64 mm = mk[u];
    while (mm){ int l = __builtin_ctzll(mm); mm &= mm - 1; d3 += d2_s[u * 64 + l]; }
  }
  const float dd = rsqrtf(fmaxf(c0 + c1 * dg + c2 * d2 + c3 * d3, 1.0f));
  if (own) dvec[g * NDIM + t] = dd;
  // z = [dd, dd*x] — two float4 stores (stride-12 rows, 16B-aligned)
  *(float4*)(zA + t * 12)     = make_float4(dd, dd * xr[0], dd * xr[1], dd * xr[2]);
  *(float4*)(zA + t * 12 + 4) = make_float4(dd * xr[3], dd * xr[4], dd * xr[5], dd * xr[6]);
  __syncthreads();
  float aw1[8], aw2[8], aw3[8];
  // w1 = A . z
  {
    float a[8] = {0,0,0,0,0,0,0,0};
    #pragma unroll
    for (int u = 0; u < 8; u++){
      u64 mm = mk[u];
      while (mm){
        int l = __builtin_ctzll(mm); mm &= mm - 1;
        const float4* p = (const float4*)(zA + (u * 64 + l) * 12);
        float4 v0 = p[0], v1 = p[1];
        a[0] += v0.x; a[1] += v0.y; a[2] += v0.z; a[3] += v0.w;
        a[4] += v1.x; a[5] += v1.y; a[6] += v1.z; a[7] += v1.w;
      }
    }
    *(float4*)(zB + t * 12)     = make_float4(a[0], a[1], a[2], a[3]);
    *(float4*)(zB + t * 12 + 4) = make_float4(a[4], a[5], a[6], a[7]);
    #pragma unroll
    for (int e = 0; e < 8; e++) aw1[e] = a[e];
  }
  __syncthreads();
  // w2 = A . w1 (reads zB; writes zA)
  {
    float a[8] = {0,0,0,0,0,0,0,0};
    #pragma unroll
    for (int u = 0; u < 8; u++){
      u64 mm = mk[u];
      while (mm){
        int l = __builtin_ctzll(mm); mm &= mm - 1;
        const float4* p = (const float4*)(zB + (u * 64 + l) * 12);
        float4 v0 = p[0], v1 = p[1];
        a[0] += v0.x; a[1] += v0.y; a[2] += v0.z; a[3] += v0.w;
        a[4] += v1.x; a[5] += v1.y; a[6] += v1.z; a[7] += v1.w;
      }
    }
    *(float4*)(zA + t * 12)     = make_float4(a[0], a[1], a[2], a[3]);
    *(float4*)(zA + t * 12 + 4) = make_float4(a[4], a[5], a[6], a[7]);
    #pragma unroll
    for (int e = 0; e < 8; e++) aw2[e] = a[e];
  }
  if (t < FIN * HID) Wl[t] = w1[t];
  if (t < HID){ Wl[448 + t] = pvec[t]; Wl[512 + t] = b1[t]; }
  __syncthreads();
  // w3 + finalize for OWN rows only
  if (own){
    #pragma unroll
    for (int e = 0; e < 8; e++) aw3[e] = 0.f;
    #pragma unroll
    for (int u = 0; u < 8; u++){
      u64 mm = mk[u];
      while (mm){
        int l = __builtin_ctzll(mm); mm &= mm - 1;
        const float4* p = (const float4*)(zA + (u * 64 + l) * 12);
        float4 v0 = p[0], v1 = p[1];
        aw3[0] += v0.x; aw3[1] += v0.y; aw3[2] += v0.z; aw3[3] += v0.w;
        aw3[4] += v1.x; aw3[5] += v1.y; aw3[6] += v1.z; aw3[7] += v1.w;
      }
    }
    const int row = g * NDIM + t;
    const float s2v = dd * (c0 * dd + c1 * aw1[0] + c2 * aw2[0] + c3 * aw3[0]);
    float yin[FIN];
    #pragma unroll
    for (int f = 0; f < FIN; f++){
      float zv = dd * xr[f];
      float y = c0 * zv;
      y += c1 * aw1[f + 1];
      y += c2 * aw2[f + 1];
      y += c3 * aw3[f + 1];
      yin[f] = dd * y;
    }
    float hv[HID];
    float s1 = 0.f;
    #pragma unroll
    for (int o = 0; o < HID; o++){
      float zz = Wl[512 + o];
      #pragma unroll
      for (int f = 0; f < FIN; f++) zz = fmaf(yin[f], Wl[f * HID + o], zz);
      hv[o] = fmaxf(zz, 0.f);
      s1 = fmaf(hv[o], Wl[448 + o], s1);
    }
    score[row] = tanhf(beta[0] * s1 + beta[1] * s2v);
    float* hr = hbuf + (size_t)row * HID;
    #pragma unroll
    for (int o = 0; o < HID; o++) hr[o] = hv[o];
  }
}

// ---- top-k rank selection + xp gather -------------------------------------
__global__ __launch_bounds__(512) void topk_kernel(const float* __restrict__ score,
                                                   const float* __restrict__ hbuf,
                                                   int* __restrict__ idxOut,
                                                   float* __restrict__ xp)
{
  const int g = blockIdx.x, t = threadIdx.x;        // 512
  __shared__ float sv[NDIM];
  sv[t] = score[g * NDIM + t];
  __syncthreads();
  const float v = sv[t];
  int rank = 0;
  #pragma unroll 8
  for (int j = 0; j < NDIM; j++){
    float u_ = sv[j];
    rank += (u_ > v || (u_ == v && j < t)) ? 1 : 0;
  }
  if (rank < KPOOL){
    idxOut[g * KPOOL + rank] = t;
    const float* hr = hbuf + ((size_t)g * NDIM + t) * HID;
    float* xr = xp + ((size_t)g * KPOOL + rank) * HID;
    #pragma unroll
    for (int o = 0; o < HID; o++) xr[o] = hr[o] * v;
  }
}

// ---- pool v3: merged-row A2p + transposed pair-packed arowT (r20 proven) --
__global__ __launch_bounds__(512) void pool_kernel(
    const u64* __restrict__ maskT, const int* __restrict__ idx,
    const float* __restrict__ dvec, const float* __restrict__ panw,
    float* __restrict__ Apool, float* __restrict__ di)
{
  const int b = blockIdx.x;
  const int g = b >> 3, rowgrp = b & 7;
  const int tid = threadIdx.x, w = tid >> 6, lane = tid & 63;
  __shared__ u64 mt[8][NDIM];                    // 32 KB
  __shared__ ushort arowT[NDIM][9];              // 9 KB (use col [w])
  __shared__ int idxs[KPOOL];
  __shared__ float dp[KPOOL];
  {
    const uint4* s4 = (const uint4*)(maskT + (size_t)g * 8 * NDIM);
    uint4* d4 = (uint4*)&mt[0][0];
    #pragma unroll
    for (int s = 0; s < 4; s++) d4[tid + 512 * s] = s4[tid + 512 * s];
  }
  if (tid < KPOOL){
    int ia = idx[g * KPOOL + tid];
    idxs[tid] = ia;
    dp[tid] = dvec[g * NDIM + ia];
  }
  __syncthreads();
  const int ir0 = idxs[rowgrp * 16 + w * 2];
  const int ir1 = idxs[rowgrp * 16 + w * 2 + 1];
  u64 rm0[8], rm1[8];
  #pragma unroll
  for (int u = 0; u < 8; u++){ rm0[u] = mt[u][ir0]; rm1[u] = mt[u][ir1]; }
  #pragma unroll
  for (int q = 0; q < 8; q++){
    const int k = q * 64 + lane;
    int p0 = 0, p1 = 0;
    #pragma unroll
    for (int u = 0; u < 8; u++){
      u64 cm = mt[u][k];
      p0 += (int)__popcll(cm & rm0[u]);
      p1 += (int)__popcll(cm & rm1[u]);
    }
    arowT[k][w] = (ushort)(p0 | (p1 << 8));
  }
  const int c0i = lane * 2, c1i = lane * 2 + 1;
  const int ic0 = idxs[c0i], ic1 = idxs[c1i];
  u64 cm0[8], cm1[8];
  #pragma unroll
  for (int u = 0; u < 8; u++){ cm0[u] = mt[u][ic0]; cm1[u] = mt[u][ic1]; }
  __syncthreads();
  int a300 = 0, a310 = 0, a301 = 0, a311 = 0;
  #pragma unroll
  for (int u = 0; u < 8; u++){
    u64 m0 = cm0[u];
    while (m0){
      int l = __builtin_ctzll(m0); m0 &= m0 - 1;
      ushort v = arowT[u * 64 + l][w];
      a300 += v & 0xFF; a310 += v >> 8;
    }
    u64 m1 = cm1[u];
    while (m1){
      int l = __builtin_ctzll(m1); m1 &= m1 - 1;
      ushort v = arowT[u * 64 + l][w];
      a301 += v & 0xFF; a311 += v >> 8;
    }
  }
  const ushort o0 = arowT[ic0][w];
  const ushort o1 = arowT[ic1][w];
  const float w0 = panw[0], ww1 = panw[1], ww2 = panw[2], ww3 = panw[3];
  const float cc0 = w0, cc1 = cc0 * ww1, cc2 = cc1 * ww2, cc3 = cc2 * ww3;
  const float dc0 = dp[c0i], dc1 = dp[c1i];
  float* Apg = Apool + (size_t)g * KPOOL * KPOOL;
  #pragma unroll
  for (int e = 0; e < 2; e++){
    const int r = rowgrp * 16 + w * 2 + e;
    const int ir = e ? ir1 : ir0;
    const float dpr = dp[r];
    const float a3c0 = (float)(e ? a310 : a300);
    const float a3c1 = (float)(e ? a311 : a301);
    const float a2c0 = (float)(e ? (o0 >> 8) : (o0 & 0xFF));
    const float a2c1 = (float)(e ? (o1 >> 8) : (o1 & 0xFF));
    float ab0 = (float)((cm0[ir >> 6] >> (ir & 63)) & 1ull);
    float ab1 = (float)((cm1[ir >> 6] >> (ir & 63)) & 1ull);
    float m0 = fmaf(cc3, a3c0, fmaf(cc2, a2c0, cc1 * ab0));
    float m1 = fmaf(cc3, a3c1, fmaf(cc2, a2c1, cc1 * ab1));
    if (r == c0i) m0 += cc0;
    if (r == c1i) m1 += cc0;
    float v0 = m0 * dpr * dc0;
    float v1 = m1 * dpr * dc1;
    if (r == c0i) v0 += 1.0f;
    if (r == c1i) v1 += 1.0f;
    *(float2*)&Apg[(size_t)r * KPOOL + c0i] = make_float2(v0, v1);
    float s = wred64(v0 + v1);
    if (lane == 0) di[g * KPOOL + r] = s > 0.f ? rsqrtf(s) : 0.f;
  }
}

// ---------------- pooled GCN: h2 = relu((An xp) W + b) ---------------------
__global__ __launch_bounds__(256) void gcn_kernel(
    const float* __restrict__ Apool, const float* __restrict__ di,
    const float* __restrict__ xp, const float* __restrict__ gw,
    const float* __restrict__ gb, float* __restrict__ h2)
{
  const int wid = threadIdx.x >> 6, lane = threadIdx.x & 63;
  const int row = blockIdx.x * 4 + wid;
  const int g = row >> 7, r = row & 127;
  const float dir = di[g * KPOOL + r];
  float acc = 0.f;
  for (int b = 0; b < KPOOL; b++){
    float an = Apool[(size_t)row * KPOOL + b] * dir * di[g * KPOOL + b];
    acc = fmaf(an, xp[((size_t)g * KPOOL + b) * HID + lane], acc);
  }
  __shared__ float ts[4][HID];
  ts[wid][lane] = acc;
  __syncthreads();
  float z = gb[lane];
  for (int f = 0; f < HID; f++) z = fmaf(ts[wid][f], gw[f * HID + lane], z);
  h2[(size_t)row * HID + lane] = fmaxf(z, 0.f);
}

// ---------------- head: pooled sum + linear + log_softmax ------------------
__global__ void head_kernel(const float* __restrict__ h2,
                            const float* __restrict__ lw,
                            const float* __restrict__ lb,
                            float* __restrict__ out)
{
  const int g = blockIdx.x;
  const int lane = threadIdx.x;
  float p = 0.f;
  for (int k = 0; k < KPOOL; k++) p += h2[((size_t)g * KPOOL + k) * HID + lane];
  float z0 = p * lw[lane * CLS + 0];
  float z1 = p * lw[lane * CLS + 1];
  z0 = wred64(z0);
  z1 = wred64(z1);
  if (lane == 0){
    float l0 = z0 + lb[0], l1 = z1 + lb[1];
    float m = fmaxf(l0, l1);
    float lse = m + logf(expf(l0 - m) + expf(l1 - m));
    out[g * CLS + 0] = l0 - lse;
    out[g * CLS + 1] = l1 - lse;
  }
}

extern "C" void kernel_launch(void* const* d_in, const int* in_sizes, int n_in,
                              void* d_out, int out_size, void* d_ws, size_t ws_size,
                              hipStream_t stream)
{
  const float* x    = (const float*)d_in[0];
  const float* adj  = (const float*)d_in[1];
  const float* panw = (const float*)d_in[2];
  const float* w1   = (const float*)d_in[3];
  const float* b1   = (const float*)d_in[4];
  const float* pvec = (const float*)d_in[5];
  const float* beta = (const float*)d_in[6];
  const float* gw   = (const float*)d_in[7];
  const float* gbv  = (const float*)d_in[8];
  const float* lw   = (const float*)d_in[9];
  const float* lb   = (const float*)d_in[10];
  float* out = (float*)d_out;

  char* ws = (char*)d_ws;
  const size_t NR = (size_t)G * NDIM;            // 32768 rows
  u64* maskT = (u64*)ws;                         // 2 MB
  char* p = ws + (1 << 21);
  float* dvec  = (float*)p;  p += NR * 4;
  float* score = (float*)p;  p += NR * 4;
  float* hbuf  = (float*)p;  p += NR * HID * 4;  // 8 MB
  int*   idx   = (int*)p;    p += (size_t)G * KPOOL * 4;
  float* xp    = (float*)p;  p += (size_t)G * KPOOL * HID * 4;
  float* Apool = (float*)p;  p += (size_t)G * KPOOL * KPOOL * 4;
  float* di    = (float*)p;  p += (size_t)G * KPOOL * 4;
  float* h2    = (float*)p;

  mask_kernel<<<G * NDIM / 4, 256, 0, stream>>>(adj, maskT);
  mega_kernel<<<256, 512, 0, stream>>>(maskT, x, panw, w1, b1, pvec, beta,
                                       dvec, score, hbuf);
  topk_kernel<<<G, 512, 0, stream>>>(score, hbuf, idx, xp);
  pool_kernel<<<G * 8, 512, 0, stream>>>(maskT, idx, dvec, panw, Apool, di);
  gcn_kernel<<<G * KPOOL / 4, 256, 0, stream>>>(Apool, di, xp, gw, gbv, h2);
  head_kernel<<<G, 64, 0, stream>>>(h2, lw, lb, out);
}